// Round 7
// baseline (441.529 us; speedup 1.0000x reference)
//
#include <hip/hip_runtime.h>
#include <hip/hip_bf16.h>

#define OUTN 11008
#define KDIM 4096
#define BDIM 32
#define NT   344          // OUTN / 32
#define WCOUNT 45088768   // OUTN * KDIM
#define G    688          // fused grid = NT * 2 K-halves (3 blocks/CU co-resident)
#define PF   4            // software-pipeline depth (power of 2)

typedef __bf16 bf16x8 __attribute__((ext_vector_type(8)));
typedef float f32x16 __attribute__((ext_vector_type(16)));

__device__ __forceinline__ ushort f2bf(float f) {
    unsigned u = __builtin_bit_cast(unsigned, f);
    u = (u + 0x7FFFu + ((u >> 16) & 1u)) >> 16;
    return (ushort)u;
}

// ternary as f32 bits: sign(w)*1.0f if |w|>d else 0
__device__ __forceinline__ unsigned tern1(float w, float d) {
    unsigned b = __builtin_bit_cast(unsigned, w);
    unsigned s = (b & 0x80000000u) | 0x3F800000u;
    return (__builtin_fabsf(w) > d) ? s : 0u;
}
// pack two ternary values as 2 bf16 (a -> low 16, b -> high 16)
__device__ __forceinline__ unsigned ternpack(float a, float b, float d) {
    return __builtin_amdgcn_perm(tern1(b, d), tern1(a, d), 0x07060302u);
}

__device__ __forceinline__ float delta_from(const double* dsum) {
    const double delta_d = 0.7 * (*dsum) * (1.0 / (double)WCOUNT);
    float dc = (float)delta_d;
    if ((double)dc > delta_d)          // largest f32 <= delta_f64
        dc = __builtin_bit_cast(float, __builtin_bit_cast(unsigned, dc) - 1u);
    return dc;
}

// device-scope grid barrier: counter in d_ws, zeroed by memset node each call
__device__ __forceinline__ void gridbar(unsigned* bar, unsigned target) {
    __syncthreads();
    __threadfence();                                   // release: publish writes
    if (threadIdx.x == 0) {
        atomicAdd(bar, 1u);
        while (__hip_atomic_load(bar, __ATOMIC_RELAXED, __HIP_MEMORY_SCOPE_AGENT) < target)
            __builtin_amdgcn_s_sleep(8);
    }
    __syncthreads();
    __threadfence();                                   // acquire
}

// ---------------- fused: xconv + abssum + barrier + ternarize-GEMM + barrier + epilogue ----
__global__ __launch_bounds__(256, 3) void fused_k(const float* __restrict__ W,
                                                  const float* __restrict__ x,
                                                  const float* __restrict__ alpha,
                                                  const float* __restrict__ bias,
                                                  float* __restrict__ out,
                                                  double* __restrict__ dsum,
                                                  unsigned* __restrict__ bar,
                                                  ushort* __restrict__ xb,
                                                  float* __restrict__ part) {
    __shared__ double redd[4];
    __shared__ float redf[3][32][32];
    const int tid = threadIdx.x;
    const int b = blockIdx.x;
    const int t = b % NT;                  // output tile (32 cols of OUT)
    const int h = b / NT;                  // K-half (0/1)
    const int lane = tid & 63, wv = tid >> 6;

    // ---- phase 0: x f32 -> bf16 fragment-ordered [K/8][32][8] (512 KB total) ----
    const int gtid = b * 256 + tid;
    if (gtid < 32768) {
        const int elem = gtid * 4;
        const int bb_ = elem >> 12;
        const int k = elem & (KDIM - 1);
        const float4 v = ((const float4*)x)[gtid];
        ushort4 o;
        o.x = f2bf(v.x); o.y = f2bf(v.y); o.z = f2bf(v.z); o.w = f2bf(v.w);
        *(ushort4*)(xb + ((k >> 3) * 32 + bb_) * 8 + (k & 7)) = o;
    }

    // ---- phase 1: f64 abs-sum over this block's own 256 KB W slice ----
    // slice: rows [32t, 32t+32), float4-cols [512h, 512h+512)
    {
        const float4* w4 = (const float4*)W;
        double s = 0.0;
#pragma unroll 8
        for (int i = 0; i < 64; ++i) {
            const int f = i * 256 + tid;               // 0..16383
            const int row = f >> 9, col = f & 511;
            float4 v = w4[(size_t)(32 * t + row) * 1024 + h * 512 + col];
            s += (double)(fabsf(v.x) + fabsf(v.y)) + (double)(fabsf(v.z) + fabsf(v.w));
        }
        for (int off = 32; off; off >>= 1) s += __shfl_down(s, off);
        if (lane == 0) redd[wv] = s;
        __syncthreads();
        if (tid == 0) atomicAdd(dsum, redd[0] + redd[1] + redd[2] + redd[3]);
    }

    gridbar(bar, G);                                   // all |W| summed, xb ready

    // ---- phase 2: ternarize + MFMA over the same (L3-hot) slice ----
    const float delta = delta_from(dsum);
    const int row = lane & 31, half = lane >> 5;
    const int kw0 = h * 2048 + wv * 512;               // this wave's K range (512)
    const float4* wp = (const float4*)(W + (size_t)(32 * t + row) * KDIM + kw0 + half * 8);
    const uint4* xa = (const uint4*)xb + ((size_t)(kw0 >> 3) + half) * 32 + row;

    f32x16 acc;
#pragma unroll
    for (int i = 0; i < 16; ++i) acc[i] = 0.0f;

    float4 Wa[PF], Wb[PF];
    uint4  XA[PF];
#pragma unroll
    for (int p = 0; p < PF; ++p) {
        Wa[p] = wp[p * 4];
        Wb[p] = wp[p * 4 + 1];
        XA[p] = xa[(size_t)p * 64];
    }
#pragma unroll
    for (int s = 0; s < 32; ++s) {                     // 32 MFMA steps of K=16
        const int bi = s & (PF - 1);                   // compile-time after unroll
        uint4 bb;
        bb.x = ternpack(Wa[bi].x, Wa[bi].y, delta);
        bb.y = ternpack(Wa[bi].z, Wa[bi].w, delta);
        bb.z = ternpack(Wb[bi].x, Wb[bi].y, delta);
        bb.w = ternpack(Wb[bi].z, Wb[bi].w, delta);
        acc = __builtin_amdgcn_mfma_f32_32x32x16_bf16(
                  __builtin_bit_cast(bf16x8, XA[bi]), __builtin_bit_cast(bf16x8, bb),
                  acc, 0, 0, 0);
        if (s + PF < 32) {
            Wa[bi] = wp[(s + PF) * 4];
            Wb[bi] = wp[(s + PF) * 4 + 1];
            XA[bi] = xa[(size_t)(s + PF) * 64];
        }
    }

    // 4-wave LDS reduce -> one partial per block into part[h]
    if (wv > 0) {
#pragma unroll
        for (int rg = 0; rg < 16; ++rg) {
            const int m = (rg & 3) + 8 * (rg >> 2) + 4 * half;
            redf[wv - 1][m][row] = acc[rg];
        }
    }
    __syncthreads();
    if (wv == 0) {
        float* po = part + (size_t)h * (BDIM * OUTN);
#pragma unroll
        for (int rg = 0; rg < 16; ++rg) {
            const int m = (rg & 3) + 8 * (rg >> 2) + 4 * half;
            po[(size_t)m * OUTN + t * 32 + row] =
                acc[rg] + redf[0][m][row] + redf[1][m][row] + redf[2][m][row];
        }
    }

    gridbar(bar, 2 * G);                               // partials visible

    // ---- phase 3: combine halves + alpha + bias (first NT blocks) ----
    if (b < NT) {
        const float a = *alpha;
        const int c = tid & 31, m0 = tid >> 5;
#pragma unroll
        for (int g = 0; g < 4; ++g) {
            const int m = m0 + g * 8;
            const int n = t * 32 + c;
            const size_t idx = (size_t)m * OUTN + n;
            out[idx] = fmaf(a, part[idx] + part[(size_t)BDIM * OUTN + idx], bias[n]);
        }
    }
}

// ---------------- fallback (tiny ws): two-pass, direct out ----------------
__global__ __launch_bounds__(256) void abssum_k(const float4* __restrict__ w4,
                                                double* __restrict__ dsum) {
    const int tid = blockIdx.x * 256 + threadIdx.x;
    double s = 0.0;
#pragma unroll 8
    for (int j = 0; j < 43; ++j) {
        float4 v = w4[tid + j * 262144];
        s += (double)(fabsf(v.x) + fabsf(v.y)) + (double)(fabsf(v.z) + fabsf(v.w));
    }
    for (int off = 32; off; off >>= 1) s += __shfl_down(s, off);
    __shared__ double red[4];
    const int lane = threadIdx.x & 63, wv = threadIdx.x >> 6;
    if (lane == 0) red[wv] = s;
    __syncthreads();
    if (threadIdx.x == 0) atomicAdd(dsum, red[0] + red[1] + red[2] + red[3]);
}

__global__ __launch_bounds__(64) void gemm1_k(const float* __restrict__ W,
                                              const float* __restrict__ x,
                                              const double* __restrict__ dsum,
                                              float* __restrict__ dst,
                                              const float* __restrict__ alpha,
                                              const float* __restrict__ bias) {
    const int l = threadIdx.x;
    const int o0 = blockIdx.x * 32;
    const float delta = delta_from(dsum);
    const int row = l & 31, half = l >> 5;
    const float4* wp = (const float4*)(W + (size_t)(o0 + row) * KDIM + half * 8);
    const float4* xp = (const float4*)(x + (size_t)row * KDIM + half * 8);

    f32x16 acc;
#pragma unroll
    for (int i = 0; i < 16; ++i) acc[i] = 0.0f;

#pragma unroll 8
    for (int s = 0; s < 256; ++s) {
        float4 w0 = wp[s * 4], w1 = wp[s * 4 + 1];
        uint4 bb;
        bb.x = ternpack(w0.x, w0.y, delta);
        bb.y = ternpack(w0.z, w0.w, delta);
        bb.z = ternpack(w1.x, w1.y, delta);
        bb.w = ternpack(w1.z, w1.w, delta);
        float4 v0 = xp[s * 4], v1 = xp[s * 4 + 1];
        struct U { ushort s[8]; } uu;
        uu.s[0] = f2bf(v0.x); uu.s[1] = f2bf(v0.y);
        uu.s[2] = f2bf(v0.z); uu.s[3] = f2bf(v0.w);
        uu.s[4] = f2bf(v1.x); uu.s[5] = f2bf(v1.y);
        uu.s[6] = f2bf(v1.z); uu.s[7] = f2bf(v1.w);
        acc = __builtin_amdgcn_mfma_f32_32x32x16_bf16(
                  __builtin_bit_cast(bf16x8, uu), __builtin_bit_cast(bf16x8, bb),
                  acc, 0, 0, 0);
    }
    const float a = *alpha;
#pragma unroll
    for (int rg = 0; rg < 16; ++rg) {
        const int m = (rg & 3) + 8 * (rg >> 2) + 4 * half;
        const int n = o0 + row;
        dst[(size_t)m * OUTN + n] = fmaf(a, acc[rg], bias[n]);
    }
}

extern "C" void kernel_launch(void* const* d_in, const int* in_sizes, int n_in,
                              void* d_out, int out_size, void* d_ws, size_t ws_size,
                              hipStream_t stream) {
    const float* x     = (const float*)d_in[0];
    const float* W     = (const float*)d_in[1];
    const float* alpha = (const float*)d_in[2];
    const float* bias  = (const float*)d_in[3];
    float* out = (float*)d_out;

    double*   dsum = (double*)d_ws;
    unsigned* bar  = (unsigned*)((char*)d_ws + 8);
    const size_t XBF_OFF  = 1024;
    const size_t XBF_SZ   = (size_t)BDIM * KDIM * 2;             // 256 KiB
    const size_t PART_OFF = XBF_OFF + XBF_SZ;
    const size_t PART_SZ  = 2 * (size_t)BDIM * OUTN * 4;         // 2.8 MiB

    if (ws_size >= PART_OFF + PART_SZ) {
        ushort* xb  = (ushort*)((char*)d_ws + XBF_OFF);
        float* part = (float*)((char*)d_ws + PART_OFF);
        (void)hipMemsetAsync(d_ws, 0, 16, stream);               // dsum + bar
        fused_k<<<G, 256, 0, stream>>>(W, x, alpha, bias, out, dsum, bar, xb, part);
    } else {
        (void)hipMemsetAsync(d_ws, 0, 16, stream);
        abssum_k<<<1024, 256, 0, stream>>>((const float4*)W, dsum);
        gemm1_k<<<NT, 64, 0, stream>>>(W, x, dsum, out, alpha, bias);
    }
}

// Round 8
// 73.499 us; speedup vs baseline: 6.0072x; 6.0072x over previous
//
#include <hip/hip_runtime.h>
#include <hip/hip_bf16.h>

#define OUTN 11008
#define KDIM 4096
#define BDIM 32
#define NT16 688          // OUTN / 16
#define WCOUNT 45088768   // OUTN * KDIM
#define PF   8            // software-pipeline depth (power of 2)

typedef __bf16 bf16x8 __attribute__((ext_vector_type(8)));
typedef float f32x4  __attribute__((ext_vector_type(4)));
typedef float f32x16 __attribute__((ext_vector_type(16)));

__device__ __forceinline__ ushort f2bf(float f) {
    unsigned u = __builtin_bit_cast(unsigned, f);
    u = (u + 0x7FFFu + ((u >> 16) & 1u)) >> 16;
    return (ushort)u;
}

// ternary as f32 bits: sign(w)*1.0f if |w|>d else 0
__device__ __forceinline__ unsigned tern1(float w, float d) {
    unsigned b = __builtin_bit_cast(unsigned, w);
    unsigned s = (b & 0x80000000u) | 0x3F800000u;
    return (__builtin_fabsf(w) > d) ? s : 0u;
}
// pack two ternary values as 2 bf16 (a -> low 16, b -> high 16)
__device__ __forceinline__ unsigned ternpack(float a, float b, float d) {
    return __builtin_amdgcn_perm(tern1(b, d), tern1(a, d), 0x07060302u);
}

__device__ __forceinline__ float delta_from(const double* dsum) {
    const double delta_d = 0.7 * (*dsum) * (1.0 / (double)WCOUNT);
    float dc = (float)delta_d;
    if ((double)dc > delta_d)          // largest f32 <= delta_f64
        dc = __builtin_bit_cast(float, __builtin_bit_cast(unsigned, dc) - 1u);
    return dc;
}

// ---------------- pass 1: abssum (f64) + x-conversion folded in ----------------
__global__ __launch_bounds__(256) void prep_k(const float4* __restrict__ w4,
                                              const float* __restrict__ x,
                                              ushort* __restrict__ xb,
                                              double* __restrict__ dsum) {
    const int tid = blockIdx.x * 256 + threadIdx.x;    // grid fixed at 1024 blocks

    // blocks 0..127: convert x f32 -> bf16 fragment-ordered [K/8][32][8]
    if (blockIdx.x < 128) {
        const int i4 = tid;                            // 0..32767 float4s
        const int elem = i4 * 4;
        const int b = elem >> 12;
        const int k = elem & (KDIM - 1);
        const float4 v = ((const float4*)x)[i4];
        ushort4 o;
        o.x = f2bf(v.x); o.y = f2bf(v.y); o.z = f2bf(v.z); o.w = f2bf(v.w);
        *(ushort4*)(xb + ((k >> 3) * 32 + b) * 8 + (k & 7)) = o;
    }

    double s = 0.0;
#pragma unroll 8
    for (int j = 0; j < 43; ++j) {                     // 262144 * 43 == WCOUNT/4
        float4 v = w4[tid + j * 262144];
        s += (double)(fabsf(v.x) + fabsf(v.y)) + (double)(fabsf(v.z) + fabsf(v.w));
    }
    for (int off = 32; off; off >>= 1) s += __shfl_down(s, off);
    __shared__ double red[4];
    const int lane = threadIdx.x & 63, wv = threadIdx.x >> 6;
    if (lane == 0) red[wv] = s;
    __syncthreads();
    if (threadIdx.x == 0) atomicAdd(dsum, red[0] + red[1] + red[2] + red[3]);
}

// ---------------- pass 2: fused ternarize + MFMA 16x16x32, full-K blocks ----------------
// 688 blocks x 256 thr (4 waves). Block = one 16-col output tile, full K=4096.
// Each wave: K quarter (1024). M=32 via two MFMAs sharing the ternarized B-frag.
// PF-deep static-indexed register pipeline; 4-way LDS reduce; alpha+bias epilogue.
__global__ __launch_bounds__(256, 3) void gemm16_k(const float* __restrict__ W,
                                                   const ushort* __restrict__ xb,
                                                   const double* __restrict__ dsum,
                                                   const float* __restrict__ alpha,
                                                   const float* __restrict__ bias,
                                                   float* __restrict__ out) {
    __shared__ float redf[3][32][16];
    const int tid = threadIdx.x;
    const int wv = tid >> 6, l = tid & 63;
    const int o0 = blockIdx.x * 16;                    // 16 output cols
    const int kw0 = wv * 1024;                         // this wave's K range

    const float delta = delta_from(dsum);
    const int col = l & 15;                            // out col AND batch row
    const int kb  = l >> 4;                            // 0..3 k-block of 8

    // W: row o0+col, k = kw0 + s*32 + kb*8  (2 float4 per step)
    const float4* wp = (const float4*)(W + (size_t)(o0 + col) * KDIM + kw0 + kb * 8);
    // X: uint4 idx = k8*32 + brow, k8 = (kw0>>3) + s*4 + kb
    const uint4* xa0 = (const uint4*)xb + ((size_t)(kw0 >> 3) + kb) * 32 + col;
    const uint4* xa1 = xa0 + 16;

    f32x4 acc0, acc1;
#pragma unroll
    for (int i = 0; i < 4; ++i) { acc0[i] = 0.0f; acc1[i] = 0.0f; }

    float4 Wa[PF], Wb[PF];
    uint4  X0[PF], X1[PF];
#pragma unroll
    for (int p = 0; p < PF; ++p) {                     // prologue: PF steps in flight
        Wa[p] = wp[p * 8];
        Wb[p] = wp[p * 8 + 1];
        X0[p] = xa0[(size_t)p * 128];
        X1[p] = xa1[(size_t)p * 128];
    }
#pragma unroll
    for (int s = 0; s < 32; ++s) {                     // 32 steps of K=32
        const int bi = s & (PF - 1);                   // compile-time after unroll
        uint4 bb;
        bb.x = ternpack(Wa[bi].x, Wa[bi].y, delta);
        bb.y = ternpack(Wa[bi].z, Wa[bi].w, delta);
        bb.z = ternpack(Wb[bi].x, Wb[bi].y, delta);
        bb.w = ternpack(Wb[bi].z, Wb[bi].w, delta);
        const bf16x8 bv = __builtin_bit_cast(bf16x8, bb);
        acc0 = __builtin_amdgcn_mfma_f32_16x16x32_bf16(
                   __builtin_bit_cast(bf16x8, X0[bi]), bv, acc0, 0, 0, 0);
        acc1 = __builtin_amdgcn_mfma_f32_16x16x32_bf16(
                   __builtin_bit_cast(bf16x8, X1[bi]), bv, acc1, 0, 0, 0);
        if (s + PF < 32) {                             // refill the slot just consumed
            Wa[bi] = wp[(s + PF) * 8];
            Wb[bi] = wp[(s + PF) * 8 + 1];
            X0[bi] = xa0[(size_t)(s + PF) * 128];
            X1[bi] = xa1[(size_t)(s + PF) * 128];
        }
    }

    // 4-wave reduce: C/D layout (16x16): col = lane&15, m = (lane>>4)*4 + reg
    if (wv > 0) {
#pragma unroll
        for (int j = 0; j < 4; ++j) {
            redf[wv - 1][kb * 4 + j][col]      = acc0[j];
            redf[wv - 1][16 + kb * 4 + j][col] = acc1[j];
        }
    }
    __syncthreads();
    if (wv == 0) {
        const float a = *alpha;
        const float bn = bias[o0 + col];
#pragma unroll
        for (int j = 0; j < 4; ++j) {
            const int m0 = kb * 4 + j;
            float v0 = acc0[j] + redf[0][m0][col] + redf[1][m0][col] + redf[2][m0][col];
            out[(size_t)m0 * OUTN + o0 + col] = fmaf(a, v0, bn);
            const int m1 = 16 + kb * 4 + j;
            float v1 = acc1[j] + redf[0][m1][col] + redf[1][m1][col] + redf[2][m1][col];
            out[(size_t)m1 * OUTN + o0 + col] = fmaf(a, v1, bn);
        }
    }
}

// ---------------- fallback (tiny ws): two-pass, direct out, 32x32x16 ----------------
__global__ __launch_bounds__(256) void abssum_k(const float4* __restrict__ w4,
                                                double* __restrict__ dsum) {
    const int tid = blockIdx.x * 256 + threadIdx.x;
    double s = 0.0;
#pragma unroll 8
    for (int j = 0; j < 43; ++j) {
        float4 v = w4[tid + j * 262144];
        s += (double)(fabsf(v.x) + fabsf(v.y)) + (double)(fabsf(v.z) + fabsf(v.w));
    }
    for (int off = 32; off; off >>= 1) s += __shfl_down(s, off);
    __shared__ double red[4];
    const int lane = threadIdx.x & 63, wv = threadIdx.x >> 6;
    if (lane == 0) red[wv] = s;
    __syncthreads();
    if (threadIdx.x == 0) atomicAdd(dsum, red[0] + red[1] + red[2] + red[3]);
}

__global__ __launch_bounds__(64) void gemm1_k(const float* __restrict__ W,
                                              const float* __restrict__ x,
                                              const double* __restrict__ dsum,
                                              float* __restrict__ dst,
                                              const float* __restrict__ alpha,
                                              const float* __restrict__ bias) {
    const int l = threadIdx.x;
    const int o0 = blockIdx.x * 32;
    const float delta = delta_from(dsum);
    const int row = l & 31, half = l >> 5;
    const float4* wp = (const float4*)(W + (size_t)(o0 + row) * KDIM + half * 8);
    const float4* xp = (const float4*)(x + (size_t)row * KDIM + half * 8);

    f32x16 acc;
#pragma unroll
    for (int i = 0; i < 16; ++i) acc[i] = 0.0f;

#pragma unroll 8
    for (int s = 0; s < 256; ++s) {
        float4 w0 = wp[s * 4], w1 = wp[s * 4 + 1];
        uint4 bb;
        bb.x = ternpack(w0.x, w0.y, delta);
        bb.y = ternpack(w0.z, w0.w, delta);
        bb.z = ternpack(w1.x, w1.y, delta);
        bb.w = ternpack(w1.z, w1.w, delta);
        float4 v0 = xp[s * 4], v1 = xp[s * 4 + 1];
        struct U { ushort s[8]; } uu;
        uu.s[0] = f2bf(v0.x); uu.s[1] = f2bf(v0.y);
        uu.s[2] = f2bf(v0.z); uu.s[3] = f2bf(v0.w);
        uu.s[4] = f2bf(v1.x); uu.s[5] = f2bf(v1.y);
        uu.s[6] = f2bf(v1.z); uu.s[7] = f2bf(v1.w);
        acc = __builtin_amdgcn_mfma_f32_32x32x16_bf16(
                  __builtin_bit_cast(bf16x8, uu), __builtin_bit_cast(bf16x8, bb),
                  acc, 0, 0, 0);
    }
    const float a = *alpha;
#pragma unroll
    for (int rg = 0; rg < 16; ++rg) {
        const int m = (rg & 3) + 8 * (rg >> 2) + 4 * half;
        const int n = o0 + row;
        dst[(size_t)m * OUTN + n] = fmaf(a, acc[rg], bias[n]);
    }
}

extern "C" void kernel_launch(void* const* d_in, const int* in_sizes, int n_in,
                              void* d_out, int out_size, void* d_ws, size_t ws_size,
                              hipStream_t stream) {
    const float* x     = (const float*)d_in[0];
    const float* W     = (const float*)d_in[1];
    const float* alpha = (const float*)d_in[2];
    const float* bias  = (const float*)d_in[3];
    float* out = (float*)d_out;

    double* dsum = (double*)d_ws;
    const size_t XBF_OFF = 1024;
    const size_t XBF_SZ  = (size_t)BDIM * KDIM * 2;              // 256 KiB

    (void)hipMemsetAsync(d_ws, 0, 16, stream);                   // zero f64 accumulator

    if (ws_size >= XBF_OFF + XBF_SZ) {
        ushort* xb = (ushort*)((char*)d_ws + XBF_OFF);
        prep_k<<<1024, 256, 0, stream>>>((const float4*)W, x, xb, dsum);
        gemm16_k<<<NT16, 256, 0, stream>>>(W, xb, dsum, alpha, bias, out);
    } else {
        abssum_k<<<1024, 256, 0, stream>>>((const float4*)W, dsum);
        gemm1_k<<<344, 64, 0, stream>>>(W, x, dsum, out, alpha, bias);
    }
}

// Round 9
// 64.307 us; speedup vs baseline: 6.8660x; 1.1430x over previous
//
#include <hip/hip_runtime.h>
#include <hip/hip_bf16.h>

#define OUTN 11008
#define KDIM 4096
#define BDIM 32
#define NT16 688          // OUTN / 16
#define WCOUNT 45088768   // OUTN * KDIM
#define PF   8            // software-pipeline depth (power of 2)
#define NPB  1024         // prep blocks / partials

typedef __bf16 bf16x8 __attribute__((ext_vector_type(8)));
typedef float f32x4  __attribute__((ext_vector_type(4)));
typedef float f32x16 __attribute__((ext_vector_type(16)));

__device__ __forceinline__ ushort f2bf(float f) {
    unsigned u = __builtin_bit_cast(unsigned, f);
    u = (u + 0x7FFFu + ((u >> 16) & 1u)) >> 16;
    return (ushort)u;
}

// ternary as f32 bits: sign(w)*1.0f if |w|>d else 0
__device__ __forceinline__ unsigned tern1(float w, float d) {
    unsigned b = __builtin_bit_cast(unsigned, w);
    unsigned s = (b & 0x80000000u) | 0x3F800000u;
    return (__builtin_fabsf(w) > d) ? s : 0u;
}
// pack two ternary values as 2 bf16 (a -> low 16, b -> high 16)
__device__ __forceinline__ unsigned ternpack(float a, float b, float d) {
    return __builtin_amdgcn_perm(tern1(b, d), tern1(a, d), 0x07060302u);
}

__device__ __forceinline__ float delta_fix(double delta_d) {
    float dc = (float)delta_d;
    if ((double)dc > delta_d)          // largest f32 <= delta_f64
        dc = __builtin_bit_cast(float, __builtin_bit_cast(unsigned, dc) - 1u);
    return dc;
}

// ---------------- pass 1: abssum partials (no atomics) + x-conversion spread ----------------
__global__ __launch_bounds__(256) void prep_k(const float4* __restrict__ w4,
                                              const float* __restrict__ x,
                                              ushort* __restrict__ xb,
                                              double* __restrict__ dpart) {
    const int tid = blockIdx.x * 256 + threadIdx.x;    // grid fixed at NPB blocks

    // x f32 -> bf16 fragment-ordered [K/8][32][8]: 32 float4s per block
    if (threadIdx.x < 32) {
        const int i4 = blockIdx.x * 32 + threadIdx.x;  // 0..32767
        const int elem = i4 * 4;
        const int b = elem >> 12;
        const int k = elem & (KDIM - 1);
        const float4 v = ((const float4*)x)[i4];
        ushort4 o;
        o.x = f2bf(v.x); o.y = f2bf(v.y); o.z = f2bf(v.z); o.w = f2bf(v.w);
        *(ushort4*)(xb + ((k >> 3) * 32 + b) * 8 + (k & 7)) = o;
    }

    double s = 0.0;
#pragma unroll 8
    for (int j = 0; j < 43; ++j) {                     // 262144 * 43 == WCOUNT/4
        float4 v = w4[tid + j * 262144];
        s += (double)(fabsf(v.x) + fabsf(v.y)) + (double)(fabsf(v.z) + fabsf(v.w));
    }
    for (int off = 32; off; off >>= 1) s += __shfl_down(s, off);
    __shared__ double red[4];
    const int lane = threadIdx.x & 63, wv = threadIdx.x >> 6;
    if (lane == 0) red[wv] = s;
    __syncthreads();
    if (threadIdx.x == 0) dpart[blockIdx.x] = red[0] + red[1] + red[2] + red[3];
}

// ---------------- pass 2: fused ternarize + MFMA 16x16x32, full-K blocks ----------------
// 688 blocks x 256 thr (4 waves). Block = one 16-col output tile, full K=4096.
// Preamble: tree-reduce the 1024 f64 partials (identical order per block).
// Each wave: K quarter (1024). M=32 via two MFMAs sharing the ternarized B-frag.
__global__ __launch_bounds__(256, 3) void gemm16_k(const float* __restrict__ W,
                                                   const ushort* __restrict__ xb,
                                                   const double* __restrict__ dpart,
                                                   const float* __restrict__ alpha,
                                                   const float* __restrict__ bias,
                                                   float* __restrict__ out) {
    __shared__ float redf[3][32][16];
    __shared__ double redd[4];
    const int tid = threadIdx.x;
    const int wv = tid >> 6, l = tid & 63;

    // ---- delta preamble: sum 1024 partials, fixed order ----
    {
        double s = 0.0;
#pragma unroll
        for (int j = 0; j < 4; ++j) s += dpart[tid * 4 + j];
        for (int off = 32; off; off >>= 1) s += __shfl_down(s, off);
        if ((tid & 63) == 0) redd[wv] = s;
    }
    __syncthreads();
    const double dsum = redd[0] + redd[1] + redd[2] + redd[3];
    const float delta = delta_fix(0.7 * dsum * (1.0 / (double)WCOUNT));

    const int o0 = blockIdx.x * 16;                    // 16 output cols
    const int kw0 = wv * 1024;                         // this wave's K range
    const int col = l & 15;                            // out col AND batch row
    const int kb  = l >> 4;                            // 0..3 k-block of 8

    // W: row o0+col, k = kw0 + s*32 + kb*8  (2 float4 per step)
    const float4* wp = (const float4*)(W + (size_t)(o0 + col) * KDIM + kw0 + kb * 8);
    // X: uint4 idx = k8*32 + brow, k8 = (kw0>>3) + s*4 + kb
    const uint4* xa0 = (const uint4*)xb + ((size_t)(kw0 >> 3) + kb) * 32 + col;
    const uint4* xa1 = xa0 + 16;

    f32x4 acc0, acc1;
#pragma unroll
    for (int i = 0; i < 4; ++i) { acc0[i] = 0.0f; acc1[i] = 0.0f; }

    float4 Wa[PF], Wb[PF];
    uint4  X0[PF], X1[PF];
#pragma unroll
    for (int p = 0; p < PF; ++p) {                     // prologue: PF steps in flight
        Wa[p] = wp[p * 8];
        Wb[p] = wp[p * 8 + 1];
        X0[p] = xa0[(size_t)p * 128];
        X1[p] = xa1[(size_t)p * 128];
    }
#pragma unroll
    for (int s = 0; s < 32; ++s) {                     // 32 steps of K=32
        const int bi = s & (PF - 1);                   // compile-time after unroll
        uint4 bb;
        bb.x = ternpack(Wa[bi].x, Wa[bi].y, delta);
        bb.y = ternpack(Wa[bi].z, Wa[bi].w, delta);
        bb.z = ternpack(Wb[bi].x, Wb[bi].y, delta);
        bb.w = ternpack(Wb[bi].z, Wb[bi].w, delta);
        const bf16x8 bv = __builtin_bit_cast(bf16x8, bb);
        acc0 = __builtin_amdgcn_mfma_f32_16x16x32_bf16(
                   __builtin_bit_cast(bf16x8, X0[bi]), bv, acc0, 0, 0, 0);
        acc1 = __builtin_amdgcn_mfma_f32_16x16x32_bf16(
                   __builtin_bit_cast(bf16x8, X1[bi]), bv, acc1, 0, 0, 0);
        if (s + PF < 32) {                             // refill the slot just consumed
            Wa[bi] = wp[(s + PF) * 8];
            Wb[bi] = wp[(s + PF) * 8 + 1];
            X0[bi] = xa0[(size_t)(s + PF) * 128];
            X1[bi] = xa1[(size_t)(s + PF) * 128];
        }
    }

    // 4-wave reduce: C/D layout (16x16): col = lane&15, m = (lane>>4)*4 + reg
    if (wv > 0) {
#pragma unroll
        for (int j = 0; j < 4; ++j) {
            redf[wv - 1][kb * 4 + j][col]      = acc0[j];
            redf[wv - 1][16 + kb * 4 + j][col] = acc1[j];
        }
    }
    __syncthreads();
    if (wv == 0) {
        const float a = *alpha;
        const float bn = bias[o0 + col];
#pragma unroll
        for (int j = 0; j < 4; ++j) {
            const int m0 = kb * 4 + j;
            float v0 = acc0[j] + redf[0][m0][col] + redf[1][m0][col] + redf[2][m0][col];
            out[(size_t)m0 * OUTN + o0 + col] = fmaf(a, v0, bn);
            const int m1 = 16 + kb * 4 + j;
            float v1 = acc1[j] + redf[0][m1][col] + redf[1][m1][col] + redf[2][m1][col];
            out[(size_t)m1 * OUTN + o0 + col] = fmaf(a, v1, bn);
        }
    }
}

// ---------------- fallback (tiny ws): two-pass, direct out, 32x32x16 ----------------
__global__ __launch_bounds__(256) void abssum_k(const float4* __restrict__ w4,
                                                double* __restrict__ dsum) {
    const int tid = blockIdx.x * 256 + threadIdx.x;
    double s = 0.0;
#pragma unroll 8
    for (int j = 0; j < 43; ++j) {
        float4 v = w4[tid + j * 262144];
        s += (double)(fabsf(v.x) + fabsf(v.y)) + (double)(fabsf(v.z) + fabsf(v.w));
    }
    for (int off = 32; off; off >>= 1) s += __shfl_down(s, off);
    __shared__ double red[4];
    const int lane = threadIdx.x & 63, wv = threadIdx.x >> 6;
    if (lane == 0) red[wv] = s;
    __syncthreads();
    if (threadIdx.x == 0) atomicAdd(dsum, red[0] + red[1] + red[2] + red[3]);
}

__global__ __launch_bounds__(64) void gemm1_k(const float* __restrict__ W,
                                              const float* __restrict__ x,
                                              const double* __restrict__ dsum,
                                              float* __restrict__ dst,
                                              const float* __restrict__ alpha,
                                              const float* __restrict__ bias) {
    const int l = threadIdx.x;
    const int o0 = blockIdx.x * 32;
    const float delta = delta_fix(0.7 * (*dsum) * (1.0 / (double)WCOUNT));
    const int row = l & 31, half = l >> 5;
    const float4* wp = (const float4*)(W + (size_t)(o0 + row) * KDIM + half * 8);
    const float4* xp = (const float4*)(x + (size_t)row * KDIM + half * 8);

    f32x16 acc;
#pragma unroll
    for (int i = 0; i < 16; ++i) acc[i] = 0.0f;

#pragma unroll 8
    for (int s = 0; s < 256; ++s) {
        float4 w0 = wp[s * 4], w1 = wp[s * 4 + 1];
        uint4 bb;
        bb.x = ternpack(w0.x, w0.y, delta);
        bb.y = ternpack(w0.z, w0.w, delta);
        bb.z = ternpack(w1.x, w1.y, delta);
        bb.w = ternpack(w1.z, w1.w, delta);
        float4 v0 = xp[s * 4], v1 = xp[s * 4 + 1];
        struct U { ushort s[8]; } uu;
        uu.s[0] = f2bf(v0.x); uu.s[1] = f2bf(v0.y);
        uu.s[2] = f2bf(v0.z); uu.s[3] = f2bf(v0.w);
        uu.s[4] = f2bf(v1.x); uu.s[5] = f2bf(v1.y);
        uu.s[6] = f2bf(v1.z); uu.s[7] = f2bf(v1.w);
        acc = __builtin_amdgcn_mfma_f32_32x32x16_bf16(
                  __builtin_bit_cast(bf16x8, uu), __builtin_bit_cast(bf16x8, bb),
                  acc, 0, 0, 0);
    }
    const float a = *alpha;
#pragma unroll
    for (int rg = 0; rg < 16; ++rg) {
        const int m = (rg & 3) + 8 * (rg >> 2) + 4 * half;
        const int n = o0 + row;
        dst[(size_t)m * OUTN + n] = fmaf(a, acc[rg], bias[n]);
    }
}

extern "C" void kernel_launch(void* const* d_in, const int* in_sizes, int n_in,
                              void* d_out, int out_size, void* d_ws, size_t ws_size,
                              hipStream_t stream) {
    const float* x     = (const float*)d_in[0];
    const float* W     = (const float*)d_in[1];
    const float* alpha = (const float*)d_in[2];
    const float* bias  = (const float*)d_in[3];
    float* out = (float*)d_out;

    const size_t PART_SZ = (size_t)NPB * 8;                      // 8 KiB partials @ 0
    const size_t XBF_OFF = 65536;
    const size_t XBF_SZ  = (size_t)BDIM * KDIM * 2;              // 256 KiB

    if (ws_size >= XBF_OFF + XBF_SZ) {
        double* dpart = (double*)d_ws;
        ushort* xb = (ushort*)((char*)d_ws + XBF_OFF);
        prep_k<<<NPB, 256, 0, stream>>>((const float4*)W, x, xb, dpart);
        gemm16_k<<<NT16, 256, 0, stream>>>(W, xb, dpart, alpha, bias, out);
    } else {
        double* dsum = (double*)d_ws;
        (void)hipMemsetAsync(d_ws, 0, 16, stream);
        abssum_k<<<1024, 256, 0, stream>>>((const float4*)W, dsum);
        gemm1_k<<<344, 64, 0, stream>>>(W, x, dsum, out, alpha, bias);
    }
}